// Round 5
// baseline (269.740 us; speedup 1.0000x reference)
//
#include <hip/hip_runtime.h>
#include <hip/hip_bf16.h>
#include <stdint.h>

// Problem constants: N=4096, K=2, E=8, D=1024, H=1024
#define N_TOK   4096
#define TOPK    2
#define N_EXP   8
#define D_MODEL 1024
#define H_DIM   1024
#define NK      (N_TOK * TOPK)   // 8192 token-copies
#define MAX_TILES 72             // sum over experts of ceil(gs/128) <= 64+7

typedef __attribute__((ext_vector_type(8))) short bf16x8;  // 8 bf16 (4 VGPRs)
typedef __attribute__((ext_vector_type(4))) float f32x4;   // MFMA accumulator
typedef unsigned short bfbits;

__device__ inline bfbits f2bf_bits(float f) {
  union { float f; unsigned int u; } v; v.f = f;
  unsigned int r = v.u + 0x7FFFu + ((v.u >> 16) & 1u);  // RNE
  return (bfbits)(r >> 16);
}
__device__ inline float bf2f(unsigned short u) {
  union { unsigned int u; float f; } v; v.u = ((unsigned int)u) << 16;
  return v.f;
}

// async global->LDS, 16B/lane; LDS dest = wave-uniform base + lane*16
__device__ inline void glds16(const bfbits* g, bfbits* l) {
  __builtin_amdgcn_global_load_lds(
      (const __attribute__((address_space(1))) void*)g,
      (__attribute__((address_space(3))) void*)l, 16, 0, 0);
}

// 64x64 transpose+convert tile helper (proven R3/R4 pattern; tl stride 65 -> 2-way banks)
__device__ inline void trans_tile64(const float* __restrict__ src, bfbits* __restrict__ dst,
                                    int r0, int c0, bfbits (*tl)[65], int tid) {
  float4 v[4];
  for (int it = 0; it < 4; it++) {
    int r = (tid >> 4) + it * 16;
    int c = (tid & 15) * 4;
    v[it] = *(const float4*)&src[(size_t)(r0 + r) * 1024 + c0 + c];
  }
  for (int it = 0; it < 4; it++) {
    int r = (tid >> 4) + it * 16;
    int c = (tid & 15) * 4;
    tl[r][c + 0] = f2bf_bits(v[it].x); tl[r][c + 1] = f2bf_bits(v[it].y);
    tl[r][c + 2] = f2bf_bits(v[it].z); tl[r][c + 3] = f2bf_bits(v[it].w);
  }
  __syncthreads();
  for (int it = 0; it < 4; it++) {
    int o = (tid >> 4) + it * 16;   // output row (= source col)
    int r4 = (tid & 15) * 4;        // source-row quad
    ushort4 w;
    w.x = tl[r4 + 0][o]; w.y = tl[r4 + 1][o];
    w.z = tl[r4 + 2][o]; w.w = tl[r4 + 3][o];
    *(ushort4*)&dst[(size_t)(c0 + o) * 1024 + r0 + r4] = w;
  }
}

// ---- fused pre-pass ----
// z == 0      : (block 0,0) ballot-based bucket sort + meta  (dispatched FIRST)
// 1 <= z < 17 : transpose+convert weight matrix z-1 (w1:0-7, w3:8-15)
// z == 17     : convert x -> bf16
// meta: [0..8] offs (excl scan), [17] ntiles, [18..89] tile_expert, [90..161] tile_row0
__global__ void prepass_kernel(const float* __restrict__ x, const int* __restrict__ eidx,
                               const int* __restrict__ bspe,
                               const float* __restrict__ w1, const float* __restrict__ w3,
                               bfbits* __restrict__ w1t, bfbits* __restrict__ w3t,
                               bfbits* __restrict__ xb,
                               int* __restrict__ meta, int* __restrict__ row_src,
                               int* __restrict__ pos_of) {
  int z = blockIdx.z;
  int tid = threadIdx.x;
  if (z == 0) {
    if (blockIdx.x != 0 || blockIdx.y != 0) return;
    __shared__ int sm[162];
    __shared__ int scnt[N_EXP];
    int lane = tid & 63;
    if (tid == 0) {
      int acc = 0, nt = 0;
      for (int e = 0; e < N_EXP; e++) {
        sm[e] = acc;
        sm[9 + e] = 0;
        int g = bspe[e];
        for (int tt = 0; tt * 128 < g; tt++) {
          sm[18 + nt] = e;
          sm[90 + nt] = acc + tt * 128;
          nt++;
        }
        acc += g;
      }
      sm[8] = acc;
      sm[17] = nt;
      for (int i = nt; i < MAX_TILES; i++) { sm[18 + i] = 0; sm[90 + i] = 0; }
    }
    if (tid < N_EXP) scnt[tid] = 0;
    __syncthreads();
    unsigned long long below = (1ULL << lane) - 1ULL;
    for (int it = 0; it < NK / 256; it++) {
      int i = it * 256 + tid;
      int e = eidx[i];
      int p = 0;
      for (int ee = 0; ee < N_EXP; ee++) {
        bool mine = (e == ee);
        unsigned long long m = __ballot(mine);
        if (m != 0ULL) {                     // wave-uniform
          int first = __ffsll(m) - 1;
          int base = 0;
          if (lane == first) base = atomicAdd(&scnt[ee], __popcll(m));
          base = __shfl(base, first);
          if (mine) p = sm[ee] + base + __popcll(m & below);
        }
      }
      row_src[p] = i;
      pos_of[i] = p;
    }
    __syncthreads();
    if (tid < 162) meta[tid] = sm[tid];
  } else if (z < 17) {
    int zm = z - 1;
    const size_t MAT = (size_t)1024 * 1024;
    const float* src = (zm < 8) ? (w1 + (size_t)zm * MAT) : (w3 + (size_t)(zm - 8) * MAT);
    bfbits* dst = (zm < 8) ? (w1t + (size_t)zm * MAT) : (w3t + (size_t)(zm - 8) * MAT);
    __shared__ bfbits tl[64][65];
    trans_tile64(src, dst, blockIdx.y * 64, blockIdx.x * 64, tl, tid);
  } else {
    int b = blockIdx.y * 16 + blockIdx.x;   // 256 blocks
    for (int it = 0; it < 16; it++) {
      int i = b * 4096 + it * 256 + tid;    // float4 index over N*D/4
      float4 v = ((const float4*)x)[i];
      ushort4 o;
      o.x = f2bf_bits(v.x); o.y = f2bf_bits(v.y);
      o.z = f2bf_bits(v.z); o.w = f2bf_bits(v.w);
      ((ushort4*)xb)[i] = o;
    }
  }
}

// ---- grouped GEMM 1: h = silu(x@w1) * (x@w3), bf16 out (NK,H) ----
// 128x64 tile, BK=64, 4 waves of 64x32, dual acc. glds staging, XOR swizzle.
// blockIdx.y >= 72: w2 transpose blocks (overlapped; w2t only needed by gemm_out).
__global__ __launch_bounds__(256, 3) void gemm_swiglu_kernel(
    const bfbits* __restrict__ xb, const bfbits* __restrict__ w1t,
    const bfbits* __restrict__ w3t, const int* __restrict__ row_src,
    const int* __restrict__ meta, bfbits* __restrict__ hb,
    const float* __restrict__ w2, bfbits* __restrict__ w2t) {
  __shared__ __align__(16) bfbits As[128 * 64];   // 16 KB
  __shared__ __align__(16) bfbits B1s[64 * 64];   //  8 KB
  __shared__ __align__(16) bfbits B3s[64 * 64];   //  8 KB
  int tid = threadIdx.x;
  int bt = blockIdx.y;
  if (bt >= MAX_TILES) {
    // w2 transpose: 2048 blocks; reuse As as the 64x65 LDS tile
    int tid2 = (bt - MAX_TILES) * 16 + blockIdx.x;
    const size_t MAT = (size_t)1024 * 1024;
    int mat = tid2 >> 8, rem = tid2 & 255;
    bfbits (*tl)[65] = (bfbits (*)[65])As;
    trans_tile64(w2 + (size_t)mat * MAT, w2t + (size_t)mat * MAT,
                 (rem >> 4) * 64, (rem & 15) * 64, tl, tid);
    return;
  }
  int nt = meta[17];
  if (bt >= nt) return;
  int e = meta[18 + bt];
  int row0 = meta[90 + bt];
  int rows_end = meta[e + 1];
  int n0 = blockIdx.x * 64;

  int lane = tid & 63, wv = tid >> 6;
  int r8 = lane >> 3, jl = lane & 7;
  int jg = jl ^ r8;   // swizzled global 16B chunk for this lane

  // 32 staging segments of 8 rows each: [0..15]=A, [16..23]=B1, [24..31]=B3
  const bfbits* gp[8]; bfbits* lp[8];
  for (int j = 0; j < 8; j++) {
    int s = wv * 8 + j;
    if (s < 16) {
      int tok = row_src[row0 + s * 8 + r8] >> 1;  // rows>=rows_end read valid junk, discarded
      gp[j] = xb + (size_t)tok * D_MODEL + jg * 8;
      lp[j] = As + s * 512;
    } else if (s < 24) {
      int b = s - 16;
      gp[j] = w1t + ((size_t)e * H_DIM + n0 + b * 8 + r8) * D_MODEL + jg * 8;
      lp[j] = B1s + b * 512;
    } else {
      int b = s - 24;
      gp[j] = w3t + ((size_t)e * H_DIM + n0 + b * 8 + r8) * D_MODEL + jg * 8;
      lp[j] = B3s + b * 512;
    }
  }

  const f32x4 fzero = {0.f, 0.f, 0.f, 0.f};
  f32x4 accg[4][2], accu[4][2];
  for (int i = 0; i < 4; i++)
    for (int j = 0; j < 2; j++) { accg[i][j] = fzero; accu[i][j] = fzero; }

  int mw = (wv & 1) * 64, nwv = (wv >> 1) * 32;
  int qd = lane >> 4, lr = lane & 15, lr7 = lr & 7;

  for (int kk = 0; kk < D_MODEL / 64; kk++) {
    int ko = kk * 64;
    for (int j = 0; j < 8; j++) glds16(gp[j] + ko, lp[j]);
    __syncthreads();
    for (int ks = 0; ks < 2; ks++) {
      int sb = ((ks * 4 + qd) ^ lr7) << 3;  // swizzled 16B slot in 64-el row
      bf16x8 af[4], b1f[2], b3f[2];
      for (int mi = 0; mi < 4; mi++)
        af[mi] = *(const bf16x8*)&As[(mw + mi * 16 + lr) * 64 + sb];
      for (int ni = 0; ni < 2; ni++) {
        b1f[ni] = *(const bf16x8*)&B1s[(nwv + ni * 16 + lr) * 64 + sb];
        b3f[ni] = *(const bf16x8*)&B3s[(nwv + ni * 16 + lr) * 64 + sb];
      }
      for (int mi = 0; mi < 4; mi++)
        for (int ni = 0; ni < 2; ni++) {
          accg[mi][ni] = __builtin_amdgcn_mfma_f32_16x16x32_bf16(af[mi], b1f[ni], accg[mi][ni], 0, 0, 0);
          accu[mi][ni] = __builtin_amdgcn_mfma_f32_16x16x32_bf16(af[mi], b3f[ni], accu[mi][ni], 0, 0, 0);
        }
    }
    __syncthreads();
  }

  // C/D layout: row=(lane>>4)*4+reg, col=lane&15
  for (int mi = 0; mi < 4; mi++) {
    int rbase = row0 + mw + mi * 16 + qd * 4;
    for (int r = 0; r < 4; r++) {
      int grow = rbase + r;
      if (grow < rows_end) {
        for (int ni = 0; ni < 2; ni++) {
          float gg = accg[mi][ni][r], u = accu[mi][ni][r];
          float h = gg / (1.f + __expf(-gg)) * u;  // silu(g)*u
          hb[(size_t)grow * H_DIM + n0 + nwv + ni * 16 + lr] = f2bf_bits(h);
        }
      }
    }
  }
}

// ---- grouped GEMM 2: out_perm(bf16) = h @ w2 ----
// 128x64 tile, BK=64, 4 waves of 64x32, single acc (32 AGPR), 4 blocks/CU.
__global__ __launch_bounds__(256, 4) void gemm_out_kernel(
    const bfbits* __restrict__ hb, const bfbits* __restrict__ w2t,
    const int* __restrict__ meta, bfbits* __restrict__ out_perm) {
  int nt = meta[17];
  int bt = blockIdx.y;
  if (bt >= nt) return;
  int e = meta[18 + bt];
  int row0 = meta[90 + bt];
  int rows_end = meta[e + 1];
  int n0 = blockIdx.x * 64;

  __shared__ __align__(16) bfbits As[128 * 64];   // 16 KB
  __shared__ __align__(16) bfbits Bs[64 * 64];    //  8 KB

  int tid = threadIdx.x, lane = tid & 63, wv = tid >> 6;
  int r8 = lane >> 3, jl = lane & 7;
  int jg = jl ^ r8;

  // 24 staging segments: [0..15]=A rows (hb, pre-sorted), [16..23]=B rows
  const bfbits* gp[6]; bfbits* lp[6];
  for (int j = 0; j < 6; j++) {
    int s = wv * 6 + j;
    if (s < 16) {
      gp[j] = hb + (size_t)(row0 + s * 8 + r8) * H_DIM + jg * 8;
      lp[j] = As + s * 512;
    } else {
      int b = s - 16;
      gp[j] = w2t + ((size_t)e * D_MODEL + n0 + b * 8 + r8) * H_DIM + jg * 8;
      lp[j] = Bs + b * 512;
    }
  }

  const f32x4 fzero = {0.f, 0.f, 0.f, 0.f};
  f32x4 acc[4][2];
  for (int i = 0; i < 4; i++)
    for (int j = 0; j < 2; j++) acc[i][j] = fzero;

  int mw = (wv & 1) * 64, nwv = (wv >> 1) * 32;
  int qd = lane >> 4, lr = lane & 15, lr7 = lr & 7;

  for (int kk = 0; kk < H_DIM / 64; kk++) {
    int ko = kk * 64;
    for (int j = 0; j < 6; j++) glds16(gp[j] + ko, lp[j]);
    __syncthreads();
    for (int ks = 0; ks < 2; ks++) {
      int sb = ((ks * 4 + qd) ^ lr7) << 3;
      bf16x8 af[4], bfr[2];
      for (int mi = 0; mi < 4; mi++)
        af[mi] = *(const bf16x8*)&As[(mw + mi * 16 + lr) * 64 + sb];
      for (int ni = 0; ni < 2; ni++)
        bfr[ni] = *(const bf16x8*)&Bs[(nwv + ni * 16 + lr) * 64 + sb];
      for (int mi = 0; mi < 4; mi++)
        for (int ni = 0; ni < 2; ni++)
          acc[mi][ni] = __builtin_amdgcn_mfma_f32_16x16x32_bf16(af[mi], bfr[ni], acc[mi][ni], 0, 0, 0);
    }
    __syncthreads();
  }

  for (int mi = 0; mi < 4; mi++) {
    int rbase = row0 + mw + mi * 16 + qd * 4;
    for (int r = 0; r < 4; r++) {
      int grow = rbase + r;
      if (grow < rows_end) {
        for (int ni = 0; ni < 2; ni++)
          out_perm[(size_t)grow * D_MODEL + n0 + nwv + ni * 16 + lr] = f2bf_bits(acc[mi][ni][r]);
      }
    }
  }
}

// ---- weighted combine of the two copies per token (bf16 in, fp32 out) ----
__global__ void combine_kernel(const ushort4* __restrict__ out_perm,
                               const int* __restrict__ pos_of,
                               const float* __restrict__ ew, float4* __restrict__ out) {
  int i = blockIdx.x * 256 + threadIdx.x;  // over N_TOK * D/4
  int tok = i >> 8;                         // D/4 = 256
  int col = i & 255;
  int p0 = pos_of[2 * tok], p1 = pos_of[2 * tok + 1];
  float w0 = ew[2 * tok], w1 = ew[2 * tok + 1];
  ushort4 a = out_perm[(size_t)p0 * 256 + col];
  ushort4 b = out_perm[(size_t)p1 * 256 + col];
  float4 o;
  o.x = w0 * bf2f(a.x) + w1 * bf2f(b.x);
  o.y = w0 * bf2f(a.y) + w1 * bf2f(b.y);
  o.z = w0 * bf2f(a.z) + w1 * bf2f(b.z);
  o.w = w0 * bf2f(a.w) + w1 * bf2f(b.w);
  out[i] = o;
}

extern "C" void kernel_launch(void* const* d_in, const int* in_sizes, int n_in,
                              void* d_out, int out_size, void* d_ws, size_t ws_size,
                              hipStream_t stream) {
  const float* x  = (const float*)d_in[0];
  const float* ew = (const float*)d_in[1];
  const int* eidx = (const int*)d_in[2];
  const int* bspe = (const int*)d_in[3];
  const float* w1 = (const float*)d_in[4];
  const float* w2 = (const float*)d_in[5];
  const float* w3 = (const float*)d_in[6];
  float* out = (float*)d_out;

  char* ws = (char*)d_ws;
  const size_t MB = 1024 * 1024;
  bfbits* w1t   = (bfbits*)(ws);             // 16 MB (E,H,D)
  bfbits* w3t   = (bfbits*)(ws + 16 * MB);   // 16 MB (E,H,D)
  bfbits* w2t   = (bfbits*)(ws + 32 * MB);   // 16 MB (E,D,H)
  bfbits* xb    = (bfbits*)(ws + 48 * MB);   //  8 MB (N,D)
  bfbits* hb    = (bfbits*)(ws + 56 * MB);   // 16 MB (NK,H)
  // out_perm (16 MB bf16) aliases w1t — dead after gemm_swiglu completes
  bfbits* out_perm = (bfbits*)(ws);
  int* row_src  = (int*)(ws + 72 * MB);              // 32 KB
  int* pos_of   = (int*)(ws + 72 * MB + 32 * 1024);  // 32 KB
  int* meta     = (int*)(ws + 72 * MB + 64 * 1024);

  prepass_kernel<<<dim3(16, 16, 18), 256, 0, stream>>>(
      x, eidx, bspe, w1, w3, w1t, w3t, xb, meta, row_src, pos_of);
  gemm_swiglu_kernel<<<dim3(H_DIM / 64, MAX_TILES + 128), 256, 0, stream>>>(
      xb, w1t, w3t, row_src, meta, hb, w2, w2t);
  gemm_out_kernel<<<dim3(D_MODEL / 64, MAX_TILES), 256, 0, stream>>>(
      hb, w2t, meta, out_perm);
  combine_kernel<<<(N_TOK * D_MODEL / 4) / 256, 256, 0, stream>>>(
      (const ushort4*)out_perm, pos_of, ew, (float4*)out);
}

// Round 6
// 251.754 us; speedup vs baseline: 1.0714x; 1.0714x over previous
//
#include <hip/hip_runtime.h>
#include <hip/hip_bf16.h>
#include <stdint.h>

// Problem constants: N=4096, K=2, E=8, D=1024, H=1024
#define N_TOK   4096
#define TOPK    2
#define N_EXP   8
#define D_MODEL 1024
#define H_DIM   1024
#define NK      (N_TOK * TOPK)   // 8192 token-copies
#define MAX_TILES 72             // sum over experts of ceil(gs/128) <= 64+7

typedef __attribute__((ext_vector_type(8))) short bf16x8;  // 8 bf16 (4 VGPRs)
typedef __attribute__((ext_vector_type(4))) float f32x4;   // MFMA accumulator
typedef unsigned short bfbits;

__device__ inline bfbits f2bf_bits(float f) {
  union { float f; unsigned int u; } v; v.f = f;
  unsigned int r = v.u + 0x7FFFu + ((v.u >> 16) & 1u);  // RNE
  return (bfbits)(r >> 16);
}
__device__ inline float bf2f(unsigned short u) {
  union { unsigned int u; float f; } v; v.u = ((unsigned int)u) << 16;
  return v.f;
}

// async global->LDS, 16B/lane; LDS dest = wave-uniform base + lane*16
__device__ inline void glds16(const bfbits* g, bfbits* l) {
  __builtin_amdgcn_global_load_lds(
      (const __attribute__((address_space(1))) void*)g,
      (__attribute__((address_space(3))) void*)l, 16, 0, 0);
}

// ---- fused pre-pass ----
// z == 0      : (block 0,0) LDS-atomic bucket sort + meta (dispatched FIRST -> hidden)
// 1 <= z < 25 : transpose+convert weight matrix z-1 (w1:0-7, w3:8-15, w2:16-23),
//               128x128 tiles, blocks with x<8 && y<8 active
// z == 25     : convert x -> bf16 (256 blocks x 16 iters)
// meta: [0..8] offs (excl scan), [17] ntiles, [18..89] tile_expert, [90..161] tile_row0
__global__ void prepass_kernel(const float* __restrict__ x, const int* __restrict__ eidx,
                               const int* __restrict__ bspe,
                               const float* __restrict__ w1, const float* __restrict__ w2,
                               const float* __restrict__ w3,
                               bfbits* __restrict__ w1t, bfbits* __restrict__ w2t,
                               bfbits* __restrict__ w3t, bfbits* __restrict__ xb,
                               int* __restrict__ meta, int* __restrict__ row_src,
                               int* __restrict__ pos_of) {
  int z = blockIdx.z;
  int tid = threadIdx.x;
  __shared__ bfbits tl[128 * 129];   // 33 KB transpose tile (pad 129: col reads 2-way/free)
  if (z == 0) {
    if (blockIdx.x != 0 || blockIdx.y != 0) return;
    __shared__ int sm[162];
    __shared__ int scnt[N_EXP];
    if (tid == 0) {
      int acc = 0, nt = 0;
      for (int e = 0; e < N_EXP; e++) {
        sm[e] = acc;
        int g = bspe[e];
        for (int tt = 0; tt * 128 < g; tt++) {
          sm[18 + nt] = e;
          sm[90 + nt] = acc + tt * 128;
          nt++;
        }
        acc += g;
      }
      sm[8] = acc;
      sm[17] = nt;
      for (int i = nt; i < MAX_TILES; i++) { sm[18 + i] = 0; sm[90 + i] = 0; }
    }
    if (tid < N_EXP) scnt[tid] = 0;
    __syncthreads();
    for (int i = tid; i < NK; i += 256) {
      int e = eidx[i];
      int p = sm[e] + atomicAdd(&scnt[e], 1);
      row_src[p] = i;
      pos_of[i] = p;
    }
    __syncthreads();
    if (tid < 162) meta[tid] = sm[tid];
  } else if (z < 25) {
    if (blockIdx.x >= 8 || blockIdx.y >= 8) return;
    int zm = z - 1;
    const size_t MAT = (size_t)1024 * 1024;
    const float* src; bfbits* dst;
    if (zm < 8)       { src = w1 + (size_t)zm * MAT;        dst = w1t + (size_t)zm * MAT; }
    else if (zm < 16) { src = w3 + (size_t)(zm - 8) * MAT;  dst = w3t + (size_t)(zm - 8) * MAT; }
    else              { src = w2 + (size_t)(zm - 16) * MAT; dst = w2t + (size_t)(zm - 16) * MAT; }
    int r0 = blockIdx.y * 128, c0 = blockIdx.x * 128;
    // phase 1: 512B-segment float4 reads, bf16 into LDS row-major
    float4 v[16];
#pragma unroll
    for (int it = 0; it < 16; it++) {
      int r = (tid >> 5) + it * 8;
      int c = (tid & 31) * 4;
      v[it] = *(const float4*)&src[(size_t)(r0 + r) * 1024 + c0 + c];
    }
#pragma unroll
    for (int it = 0; it < 16; it++) {
      int r = (tid >> 5) + it * 8;
      int c = (tid & 31) * 4;
      tl[r * 129 + c + 0] = f2bf_bits(v[it].x);
      tl[r * 129 + c + 1] = f2bf_bits(v[it].y);
      tl[r * 129 + c + 2] = f2bf_bits(v[it].z);
      tl[r * 129 + c + 3] = f2bf_bits(v[it].w);
    }
    __syncthreads();
    // phase 2: column reads (bank = lane mod 32, 2-way free), 256B ushort2 stores
    int l = tid & 63, wv = tid >> 6;
#pragma unroll 4
    for (int it = 0; it < 32; it++) {
      int o = wv + it * 4;                  // source col = output row
      ushort2 s;
      s.x = tl[(2 * l) * 129 + o];
      s.y = tl[(2 * l + 1) * 129 + o];
      *(ushort2*)&dst[(size_t)(c0 + o) * 1024 + r0 + 2 * l] = s;
    }
  } else {
    int b = blockIdx.y * 16 + blockIdx.x;   // 256 blocks
    for (int it = 0; it < 16; it++) {
      int i = b * 4096 + it * 256 + tid;    // float4 index over N*D/4
      float4 v = ((const float4*)x)[i];
      ushort4 o;
      o.x = f2bf_bits(v.x); o.y = f2bf_bits(v.y);
      o.z = f2bf_bits(v.z); o.w = f2bf_bits(v.w);
      ((ushort4*)xb)[i] = o;
    }
  }
}

// ---- grouped GEMM 1: h = silu(x@w1) * (x@w3), bf16 out (NK,H) ----
// 128x64 tile, BK=64, 4 waves of 64x32, dual acc. glds staging, XOR swizzle.
__global__ __launch_bounds__(256, 3) void gemm_swiglu_kernel(
    const bfbits* __restrict__ xb, const bfbits* __restrict__ w1t,
    const bfbits* __restrict__ w3t, const int* __restrict__ row_src,
    const int* __restrict__ meta, bfbits* __restrict__ hb) {
  int nt = meta[17];
  int bt = blockIdx.y;
  if (bt >= nt) return;
  int e = meta[18 + bt];
  int row0 = meta[90 + bt];
  int rows_end = meta[e + 1];
  int n0 = blockIdx.x * 64;

  __shared__ __align__(16) bfbits As[128 * 64];   // 16 KB
  __shared__ __align__(16) bfbits B1s[64 * 64];   //  8 KB
  __shared__ __align__(16) bfbits B3s[64 * 64];   //  8 KB

  int tid = threadIdx.x, lane = tid & 63, wv = tid >> 6;
  int r8 = lane >> 3, jl = lane & 7;
  int jg = jl ^ r8;   // swizzled global 16B chunk for this lane

  // 32 staging segments of 8 rows each: [0..15]=A, [16..23]=B1, [24..31]=B3
  const bfbits* gp[8]; bfbits* lp[8];
  for (int j = 0; j < 8; j++) {
    int s = wv * 8 + j;
    if (s < 16) {
      // rows >= rows_end may index row_src[8192..8318] -> lands in pos_of
      // (values < 8192) by ws layout, so gathers stay in-bounds; discarded later.
      int tok = row_src[row0 + s * 8 + r8] >> 1;  // TOPK=2
      gp[j] = xb + (size_t)tok * D_MODEL + jg * 8;
      lp[j] = As + s * 512;
    } else if (s < 24) {
      int b = s - 16;
      gp[j] = w1t + ((size_t)e * H_DIM + n0 + b * 8 + r8) * D_MODEL + jg * 8;
      lp[j] = B1s + b * 512;
    } else {
      int b = s - 24;
      gp[j] = w3t + ((size_t)e * H_DIM + n0 + b * 8 + r8) * D_MODEL + jg * 8;
      lp[j] = B3s + b * 512;
    }
  }

  const f32x4 fzero = {0.f, 0.f, 0.f, 0.f};
  f32x4 accg[4][2], accu[4][2];
  for (int i = 0; i < 4; i++)
    for (int j = 0; j < 2; j++) { accg[i][j] = fzero; accu[i][j] = fzero; }

  int mw = (wv & 1) * 64, nwv = (wv >> 1) * 32;
  int qd = lane >> 4, lr = lane & 15, lr7 = lr & 7;

  for (int kk = 0; kk < D_MODEL / 64; kk++) {
    int ko = kk * 64;
    for (int j = 0; j < 8; j++) glds16(gp[j] + ko, lp[j]);
    __syncthreads();
    for (int ks = 0; ks < 2; ks++) {
      int sb = ((ks * 4 + qd) ^ lr7) << 3;  // swizzled 16B slot in 64-el row
      bf16x8 af[4], b1f[2], b3f[2];
      for (int mi = 0; mi < 4; mi++)
        af[mi] = *(const bf16x8*)&As[(mw + mi * 16 + lr) * 64 + sb];
      for (int ni = 0; ni < 2; ni++) {
        b1f[ni] = *(const bf16x8*)&B1s[(nwv + ni * 16 + lr) * 64 + sb];
        b3f[ni] = *(const bf16x8*)&B3s[(nwv + ni * 16 + lr) * 64 + sb];
      }
      for (int mi = 0; mi < 4; mi++)
        for (int ni = 0; ni < 2; ni++) {
          accg[mi][ni] = __builtin_amdgcn_mfma_f32_16x16x32_bf16(af[mi], b1f[ni], accg[mi][ni], 0, 0, 0);
          accu[mi][ni] = __builtin_amdgcn_mfma_f32_16x16x32_bf16(af[mi], b3f[ni], accu[mi][ni], 0, 0, 0);
        }
    }
    __syncthreads();
  }

  // C/D layout: row=(lane>>4)*4+reg, col=lane&15
  for (int mi = 0; mi < 4; mi++) {
    int rbase = row0 + mw + mi * 16 + qd * 4;
    for (int r = 0; r < 4; r++) {
      int grow = rbase + r;
      if (grow < rows_end) {
        for (int ni = 0; ni < 2; ni++) {
          float gg = accg[mi][ni][r], u = accu[mi][ni][r];
          float h = gg / (1.f + __expf(-gg)) * u;  // silu(g)*u
          hb[(size_t)grow * H_DIM + n0 + nwv + ni * 16 + lr] = f2bf_bits(h);
        }
      }
    }
  }
}

// ---- grouped GEMM 2: out_perm(bf16) = h @ w2 ----
// 128x64 tile, BK=64, 4 waves of 64x32, single acc (32 AGPR), 4 blocks/CU.
__global__ __launch_bounds__(256, 4) void gemm_out_kernel(
    const bfbits* __restrict__ hb, const bfbits* __restrict__ w2t,
    const int* __restrict__ meta, bfbits* __restrict__ out_perm) {
  int nt = meta[17];
  int bt = blockIdx.y;
  if (bt >= nt) return;
  int e = meta[18 + bt];
  int row0 = meta[90 + bt];
  int rows_end = meta[e + 1];
  int n0 = blockIdx.x * 64;

  __shared__ __align__(16) bfbits As[128 * 64];   // 16 KB
  __shared__ __align__(16) bfbits Bs[64 * 64];    //  8 KB

  int tid = threadIdx.x, lane = tid & 63, wv = tid >> 6;
  int r8 = lane >> 3, jl = lane & 7;
  int jg = jl ^ r8;

  // 24 staging segments: [0..15]=A rows (hb, pre-sorted), [16..23]=B rows
  const bfbits* gp[6]; bfbits* lp[6];
  for (int j = 0; j < 6; j++) {
    int s = wv * 6 + j;
    if (s < 16) {
      gp[j] = hb + (size_t)(row0 + s * 8 + r8) * H_DIM + jg * 8;
      lp[j] = As + s * 512;
    } else {
      int b = s - 16;
      gp[j] = w2t + ((size_t)e * D_MODEL + n0 + b * 8 + r8) * H_DIM + jg * 8;
      lp[j] = Bs + b * 512;
    }
  }

  const f32x4 fzero = {0.f, 0.f, 0.f, 0.f};
  f32x4 acc[4][2];
  for (int i = 0; i < 4; i++)
    for (int j = 0; j < 2; j++) acc[i][j] = fzero;

  int mw = (wv & 1) * 64, nwv = (wv >> 1) * 32;
  int qd = lane >> 4, lr = lane & 15, lr7 = lr & 7;

  for (int kk = 0; kk < H_DIM / 64; kk++) {
    int ko = kk * 64;
    for (int j = 0; j < 6; j++) glds16(gp[j] + ko, lp[j]);
    __syncthreads();
    for (int ks = 0; ks < 2; ks++) {
      int sb = ((ks * 4 + qd) ^ lr7) << 3;
      bf16x8 af[4], bfr[2];
      for (int mi = 0; mi < 4; mi++)
        af[mi] = *(const bf16x8*)&As[(mw + mi * 16 + lr) * 64 + sb];
      for (int ni = 0; ni < 2; ni++)
        bfr[ni] = *(const bf16x8*)&Bs[(nwv + ni * 16 + lr) * 64 + sb];
      for (int mi = 0; mi < 4; mi++)
        for (int ni = 0; ni < 2; ni++)
          acc[mi][ni] = __builtin_amdgcn_mfma_f32_16x16x32_bf16(af[mi], bfr[ni], acc[mi][ni], 0, 0, 0);
    }
    __syncthreads();
  }

  for (int mi = 0; mi < 4; mi++) {
    int rbase = row0 + mw + mi * 16 + qd * 4;
    for (int r = 0; r < 4; r++) {
      int grow = rbase + r;
      if (grow < rows_end) {
        for (int ni = 0; ni < 2; ni++)
          out_perm[(size_t)grow * D_MODEL + n0 + nwv + ni * 16 + lr] = f2bf_bits(acc[mi][ni][r]);
      }
    }
  }
}

// ---- weighted combine of the two copies per token (bf16 in, fp32 out) ----
__global__ void combine_kernel(const ushort4* __restrict__ out_perm,
                               const int* __restrict__ pos_of,
                               const float* __restrict__ ew, float4* __restrict__ out) {
  int i = blockIdx.x * 256 + threadIdx.x;  // over N_TOK * D/4
  int tok = i >> 8;                         // D/4 = 256
  int col = i & 255;
  int p0 = pos_of[2 * tok], p1 = pos_of[2 * tok + 1];
  float w0 = ew[2 * tok], w1 = ew[2 * tok + 1];
  ushort4 a = out_perm[(size_t)p0 * 256 + col];
  ushort4 b = out_perm[(size_t)p1 * 256 + col];
  float4 o;
  o.x = w0 * bf2f(a.x) + w1 * bf2f(b.x);
  o.y = w0 * bf2f(a.y) + w1 * bf2f(b.y);
  o.z = w0 * bf2f(a.z) + w1 * bf2f(b.z);
  o.w = w0 * bf2f(a.w) + w1 * bf2f(b.w);
  out[i] = o;
}

extern "C" void kernel_launch(void* const* d_in, const int* in_sizes, int n_in,
                              void* d_out, int out_size, void* d_ws, size_t ws_size,
                              hipStream_t stream) {
  const float* x  = (const float*)d_in[0];
  const float* ew = (const float*)d_in[1];
  const int* eidx = (const int*)d_in[2];
  const int* bspe = (const int*)d_in[3];
  const float* w1 = (const float*)d_in[4];
  const float* w2 = (const float*)d_in[5];
  const float* w3 = (const float*)d_in[6];
  float* out = (float*)d_out;

  char* ws = (char*)d_ws;
  const size_t MB = 1024 * 1024;
  bfbits* w1t   = (bfbits*)(ws);             // 16 MB (E,H,D)
  bfbits* w3t   = (bfbits*)(ws + 16 * MB);   // 16 MB (E,H,D)
  bfbits* w2t   = (bfbits*)(ws + 32 * MB);   // 16 MB (E,D,H)
  bfbits* xb    = (bfbits*)(ws + 48 * MB);   //  8 MB (N,D)
  bfbits* hb    = (bfbits*)(ws + 56 * MB);   // 16 MB (NK,H)
  // out_perm (16 MB bf16) aliases w1t — dead after gemm_swiglu completes
  bfbits* out_perm = (bfbits*)(ws);
  // LAYOUT INVARIANT: pos_of must directly follow row_src (tile-tail gathers
  // read row_src[8192..8318] which lands in pos_of, values < 8192 -> in-bounds)
  int* row_src  = (int*)(ws + 72 * MB);              // 32 KB
  int* pos_of   = (int*)(ws + 72 * MB + 32 * 1024);  // 32 KB
  int* meta     = (int*)(ws + 72 * MB + 64 * 1024);

  prepass_kernel<<<dim3(16, 16, 26), 256, 0, stream>>>(
      x, eidx, bspe, w1, w2, w3, w1t, w2t, w3t, xb, meta, row_src, pos_of);
  gemm_swiglu_kernel<<<dim3(H_DIM / 64, MAX_TILES), 256, 0, stream>>>(
      xb, w1t, w3t, row_src, meta, hb);
  gemm_out_kernel<<<dim3(D_MODEL / 64, MAX_TILES), 256, 0, stream>>>(
      hb, w2t, meta, out_perm);
  combine_kernel<<<(N_TOK * D_MODEL / 4) / 256, 256, 0, stream>>>(
      (const ushort4*)out_perm, pos_of, ew, (float4*)out);
}